// Round 16
// baseline (197.558 us; speedup 1.0000x reference)
//
#include <hip/hip_runtime.h>
#include <hip/hip_bf16.h>

typedef __attribute__((ext_vector_type(8))) short short8;
typedef __attribute__((ext_vector_type(8))) _Float16 half8;
typedef __attribute__((ext_vector_type(4))) float f32x4;
typedef __attribute__((ext_vector_type(16))) float f32x16;
typedef __attribute__((ext_vector_type(4))) unsigned int uint4v;
typedef __attribute__((ext_vector_type(2))) unsigned int uint2v;

#define NB 4
#define NH 16
#define NS 2048
#define ND 1024
#define NM 64
#define R_TOT 8192            // NB*NS
#define N_QKV 3072
#define QKV_ONE 8388608       // NB*NH*NS*NM
#define SCALE_Q 0.18033688011112042f   // (1/8)*log2(e)

static __device__ __forceinline__ unsigned short f2h(float f) {
    _Float16 h = (_Float16)f;   // v_cvt_f16_f32, RNE
    return __builtin_bit_cast(unsigned short, h);
}
static __device__ __forceinline__ unsigned cvtpk_h(float lo, float hiv) {
    unsigned r;   // D.lo = f16(S0), D.hi = f16(S1)
    asm("v_cvt_pkrtz_f16_f32 %0, %1, %2" : "=v"(r) : "v"(lo), "v"(hiv));
    return r;
}
static __device__ __forceinline__ void gl_lds16(const unsigned short* g, unsigned short* l) {
    __builtin_amdgcn_global_load_lds((const __attribute__((address_space(1))) void*)g,
                                     (__attribute__((address_space(3))) void*)l, 16, 0, 0);
}
// swizzled LDS read: tile rows are 64 shorts = 128B = 8 x 16B chunks, XOR chunk with (row&7)
static __device__ __forceinline__ half8 rd_swz(const unsigned short* base, int row, int col) {
    int byte = (row << 7) + (col << 1);
    byte ^= (row & 7) << 4;
    return *(const half8*)((const char*)base + byte);
}

// ---------------- conversions ----------------
__global__ __launch_bounds__(256) void k_convert_x(const float* __restrict__ x,
                                                   unsigned short* __restrict__ xh) {
    int i = blockIdx.x * 256 + threadIdx.x;
    const float4* xp = (const float4*)x;
    float4 v = xp[i];
    ushort4 o;
    o.x = f2h(v.x); o.y = f2h(v.y); o.z = f2h(v.z); o.w = f2h(v.w);
    ((ushort4*)xh)[i] = o;
}

__global__ __launch_bounds__(256) void k_convert_wqkv(const float* __restrict__ Wq,
                                                      const float* __restrict__ Wk,
                                                      const float* __restrict__ Wv,
                                                      unsigned short* __restrict__ BT) {
    int i = blockIdx.x * 256 + threadIdx.x;   // i = n*1024 + d
    int d = i & 1023;
    int n = i >> 10;
    int w = n >> 10;
    int h = (n >> 6) & 15;
    int m = n & 63;
    const float* W = (w == 0) ? Wq : ((w == 1) ? Wk : Wv);
    float v = W[((size_t)h * ND + d) * NM + m];
    if (w == 0) v *= SCALE_Q;
    BT[i] = f2h(v);
}

__global__ __launch_bounds__(256) void k_convert_wo(const float* __restrict__ Wo,
                                                    unsigned short* __restrict__ BTo) {
    int i = blockIdx.x * 256 + threadIdx.x;   // i = d*1024 + n
    int n = i & 1023;
    int d = i >> 10;
    BTo[i] = f2h(Wo[(size_t)n * ND + d]);
}

// ---------------- QKV projection GEMM: 256x192 tile + attn-proven pipeline protocol --------
// 2-deep prefetch, counted vmcnt(7) (7 gl_lds/wave/tile), dual barrier, stage after barrier2.
#define QBM 256
#define QBN 192
__global__ __launch_bounds__(512, 2) void k_gemm_qkv(const unsigned short* __restrict__ A,
                                                     const unsigned short* __restrict__ BT,
                                                     unsigned short* __restrict__ qkv) {
    __shared__ unsigned short L[2][(QBM + QBN) * 64];   // A rows 0..255, B rows 0..191
    int tid = threadIdx.x;
    int bx = blockIdx.x;
    int swz = (bx & 7) * 64 + (bx >> 3);   // XCD swizzle, bijective (512 = 8*64)
    int rt = swz & 31;                      // 32 row tiles
    int ct = swz >> 5;                      // 16 col tiles
    int r0 = rt * QBM, c0 = ct * QBN;
    int lane = tid & 63, wid = tid >> 6;
    int l15 = lane & 15, grp = lane >> 4;
    int wrow = (wid >> 2) * 128;            // 2 wave-rows
    int wcol = (wid & 3) * 48;              // 4 wave-cols

    f32x4 acc[8][3] = {};

    auto stageA = [&](int bufi, int k0) {
        #pragma unroll
        for (int r = 0; r < 4; ++r) {
            int off = r * 4096 + tid * 8;
            int row = off >> 6;
            int sch = ((off >> 3) & 7) ^ (row & 7);
            gl_lds16(A + (size_t)(r0 + row) * 1024 + k0 + sch * 8, &L[bufi][off]);
        }
    };
    auto stageB = [&](int bufi, int k0) {
        #pragma unroll
        for (int r = 0; r < 3; ++r) {
            int off = r * 4096 + tid * 8;
            int row = off >> 6;
            int sch = ((off >> 3) & 7) ^ (row & 7);
            gl_lds16(BT + (size_t)(c0 + row) * 1024 + k0 + sch * 8, &L[bufi][QBM * 64 + off]);
        }
    };

    // 2-deep prefetch; never drain vmcnt in steady state (attn-proven protocol)
    stageA(0, 0);   stageB(0, 0);
    stageA(1, 64);  stageB(1, 64);

    for (int t = 0; t < 16; ++t) {
        int buf = t & 1;
        if (t < 15) asm volatile("s_waitcnt vmcnt(7)" ::: "memory");
        else        asm volatile("s_waitcnt vmcnt(0)" ::: "memory");
        __builtin_amdgcn_s_barrier();          // tile t fully in LDS (each wave drained own 7)
        __builtin_amdgcn_sched_barrier(0);
        const unsigned short* As = L[buf];
        const unsigned short* Bs = L[buf] + QBM * 64;

        half8 af[8], bf[3];
        #pragma unroll
        for (int i = 0; i < 8; ++i) af[i] = rd_swz(As, wrow + i * 16 + l15, grp * 8);
        #pragma unroll
        for (int j = 0; j < 3; ++j) bf[j] = rd_swz(Bs, wcol + j * 16 + l15, grp * 8);
        __builtin_amdgcn_s_setprio(1);
        #pragma unroll
        for (int i = 0; i < 8; ++i)
            #pragma unroll
            for (int j = 0; j < 3; ++j)
                acc[i][j] = __builtin_amdgcn_mfma_f32_16x16x32_f16(af[i], bf[j], acc[i][j], 0, 0, 0);
        __builtin_amdgcn_s_setprio(0);

        #pragma unroll
        for (int i = 0; i < 8; ++i) af[i] = rd_swz(As, wrow + i * 16 + l15, 32 + grp * 8);
        #pragma unroll
        for (int j = 0; j < 3; ++j) bf[j] = rd_swz(Bs, wcol + j * 16 + l15, 32 + grp * 8);
        __builtin_amdgcn_s_setprio(1);
        #pragma unroll
        for (int i = 0; i < 8; ++i)
            #pragma unroll
            for (int j = 0; j < 3; ++j)
                acc[i][j] = __builtin_amdgcn_mfma_f32_16x16x32_f16(af[i], bf[j], acc[i][j], 0, 0, 0);
        __builtin_amdgcn_s_setprio(0);

        __builtin_amdgcn_sched_barrier(0);
        __builtin_amdgcn_s_barrier();          // all waves done reading buf -> safe to overwrite
        if (t < 14) { stageA(buf, (t + 2) * 64); stageB(buf, (t + 2) * 64); }
    }

    #pragma unroll
    for (int j = 0; j < 3; ++j) {
        int n_base = c0 + wcol + j * 16;
        int w = n_base >> 10;
        int nh = n_base + l15;
        int h = (nh >> 6) & 15;
        int m = nh & 63;
        if (w == 2) {
            unsigned short* outp = qkv + 2 * (size_t)QKV_ONE;
            #pragma unroll
            for (int i = 0; i < 8; ++i) {
                int rb = r0 + wrow + i * 16 + grp * 4;
                int bb = rb >> 11, s = rb & 2047;
                ushort4 pv;
                pv.x = f2h(acc[i][j][0]);
                pv.y = f2h(acc[i][j][1]);
                pv.z = f2h(acc[i][j][2]);
                pv.w = f2h(acc[i][j][3]);
                *(ushort4*)(outp + ((size_t)(bb * NH + h) * NM + m) * NS + s) = pv;
            }
        } else {
            unsigned short* outp = qkv + (size_t)w * QKV_ONE;
            #pragma unroll
            for (int i = 0; i < 8; ++i) {
                int rb = r0 + wrow + i * 16 + grp * 4;
                #pragma unroll
                for (int reg = 0; reg < 4; ++reg) {
                    int r = rb + reg;
                    int bb = r >> 11, s = r & 2047;
                    outp[((size_t)(bb * NH + h) * NS + s) * NM + m] = f2h(acc[i][j][reg]);
                }
            }
        }
    }
}

// ---------------- flash attention: R13-exact (8 waves, proven) ----------------
__global__ __launch_bounds__(512) void k_attn(const unsigned short* __restrict__ qkv,
                                              unsigned short* __restrict__ ctx) {
    __shared__ unsigned short Ks[2][4096];   // [t][m] 64x64, chunk-swizzled
    __shared__ unsigned short Vs[2][4096];   // [m][t] 64x64 (V^T), chunk-swizzled

    int tid = threadIdx.x;
    int lane = tid & 63, wid = tid >> 6;     // 8 waves
    int l31 = lane & 31, hi = lane >> 5;

    int bid = blockIdx.x;                    // 512 blocks
    int xcd = bid & 7;                       // one head-group per XCD for L2 reuse
    int j = bid >> 3;                        // 0..63
    int bh = xcd * 8 + (j >> 3);
    int qb = j & 7;                          // 0..7
    int b = bh >> 4, h = bh & 15;

    size_t hb = (size_t)bh * NS * NM;
    const unsigned short* Qg = qkv + hb;
    const unsigned short* Kg = qkv + QKV_ONE + hb;
    const unsigned short* Vt = qkv + 2 * (size_t)QKV_ONE + hb;

    int q0 = qb * 256 + wid * 32;

    half8 qf[4];
    #pragma unroll
    for (int kk = 0; kk < 4; ++kk)
        qf[kk] = *(const half8*)(Qg + (size_t)(q0 + l31) * NM + kk * 16 + hi * 8);

    half8 ones;
    #pragma unroll
    for (int e = 0; e < 8; ++e) ones[e] = (_Float16)1.0f;

    f32x16 accO0 = {}, accO1 = {}, accS = {};

    // staging: 16 segs of 1KB; wave w owns segs {2w, 2w+1}; segs 0-7 = K, 8-15 = V
    const unsigned short* gsrc0;
    const unsigned short* gsrc1;
    unsigned short* lbase0;
    unsigned short* lbase1;
    int step0, step1;
    {
        int seg = wid * 2;
        int off = (seg & 7) * 512 + lane * 8;
        int row = off >> 6;
        int sch = ((off >> 3) & 7) ^ (row & 7);
        if (seg < 8) { gsrc0 = Kg + row * NM + sch * 8; step0 = NM;  lbase0 = &Ks[0][off]; }
        else         { gsrc0 = Vt + (size_t)row * NS + sch * 8; step0 = 1; lbase0 = &Vs[0][off]; }
        seg = wid * 2 + 1;
        off = (seg & 7) * 512 + lane * 8;
        row = off >> 6;
        sch = ((off >> 3) & 7) ^ (row & 7);
        if (seg < 8) { gsrc1 = Kg + row * NM + sch * 8; step1 = NM;  lbase1 = &Ks[0][off]; }
        else         { gsrc1 = Vt + (size_t)row * NS + sch * 8; step1 = 1; lbase1 = &Vs[0][off]; }
    }
    auto stage = [&](int bufi, int t0) {
        gl_lds16(gsrc0 + (size_t)t0 * step0, lbase0 + bufi * 4096);
        gl_lds16(gsrc1 + (size_t)t0 * step1, lbase1 + bufi * 4096);
    };

    // 2-deep prefetch; counted vmcnt (2 loads/wave/tile)
    stage(0, 0);
    stage(1, 64);

    for (int t = 0; t < 32; ++t) {
        int buf = t & 1;
        if (t < 31) asm volatile("s_waitcnt vmcnt(2)" ::: "memory");
        else        asm volatile("s_waitcnt vmcnt(0)" ::: "memory");
        __builtin_amdgcn_s_barrier();          // all 16 segs of tile t in LDS
        __builtin_amdgcn_sched_barrier(0);
        const unsigned short* Kb = Ks[buf];
        const unsigned short* Vb = Vs[buf];

        // S^T[t][q] = mfma(K, Q): col = q = l31, row t' = (reg&3)+8*(reg>>2)+4*hi
        f32x16 s0v = {}, s1v = {};
        __builtin_amdgcn_s_setprio(1);
        #pragma unroll
        for (int kk = 0; kk < 4; ++kk) {
            int col = kk * 16 + hi * 8;
            s0v = __builtin_amdgcn_mfma_f32_32x32x16_f16(rd_swz(Kb, l31, col), qf[kk], s0v, 0, 0, 0);
            s1v = __builtin_amdgcn_mfma_f32_32x32x16_f16(rd_swz(Kb, 32 + l31, col), qf[kk], s1v, 0, 0, 0);
        }
        __builtin_amdgcn_s_setprio(0);

        // exp2 (Q pre-scaled by log2e/8), pack to fp16 pairs (denominator via ones-MFMA)
        unsigned pk0[8], pk1[8];
        #pragma unroll
        for (int jj = 0; jj < 8; ++jj) {
            float a0 = __builtin_amdgcn_exp2f(s0v[2 * jj]);
            float b0 = __builtin_amdgcn_exp2f(s0v[2 * jj + 1]);
            float a1 = __builtin_amdgcn_exp2f(s1v[2 * jj]);
            float b1 = __builtin_amdgcn_exp2f(s1v[2 * jj + 1]);
            pk0[jj] = cvtpk_h(a0, b0);
            pk1[jj] = cvtpk_h(a1, b1);
        }

        // PV A-fragment via hazard-modeled builtin permlane32_swap (vdst.hi <-> vsrc.lo)
        __builtin_amdgcn_s_setprio(1);
        #pragma unroll
        for (int kt = 0; kt < 4; ++kt) {
            unsigned w0, w1, w2, w3;
            if (kt < 2) {
                int base = (kt & 1) * 4;
                w0 = pk0[base + 0]; w1 = pk0[base + 1];
                w2 = pk0[base + 2]; w3 = pk0[base + 3];
            } else {
                int base = (kt & 1) * 4;
                w0 = pk1[base + 0]; w1 = pk1[base + 1];
                w2 = pk1[base + 2]; w3 = pk1[base + 3];
            }
            uint2v r02 = __builtin_amdgcn_permlane32_swap(w0, w2, false, false);
            uint2v r13 = __builtin_amdgcn_permlane32_swap(w1, w3, false, false);
            uint4v av;
            av[0] = r02[0]; av[1] = r13[0]; av[2] = r02[1]; av[3] = r13[1];
            half8 af = __builtin_bit_cast(half8, av);
            int col = kt * 16 + hi * 8;
            accO0 = __builtin_amdgcn_mfma_f32_32x32x16_f16(af, rd_swz(Vb, l31, col), accO0, 0, 0, 0);
            accO1 = __builtin_amdgcn_mfma_f32_32x32x16_f16(af, rd_swz(Vb, 32 + l31, col), accO1, 0, 0, 0);
            accS  = __builtin_amdgcn_mfma_f32_32x32x16_f16(af, ones, accS, 0, 0, 0);
        }
        __builtin_amdgcn_s_setprio(0);

        __builtin_amdgcn_sched_barrier(0);
        __builtin_amdgcn_s_barrier();          // all waves done READING buf -> safe to overwrite
        if (t < 30) stage(buf, (t + 2) * 64);
    }

    // denominators in accS (same (reg,hi)->q map as accO) -- fully in-register
    #pragma unroll
    for (int reg = 0; reg < 16; ++reg) {
        int q = (reg & 3) + 8 * (reg >> 2) + 4 * hi;
        float linv = 1.0f / accS[reg];
        size_t ob = ((size_t)b * NS + (q0 + q)) * ND + h * 64 + l31;
        ctx[ob] = f2h(accO0[reg] * linv);
        ctx[ob + 32] = f2h(accO1[reg] * linv);
    }
}

// ---------------- output projection GEMM: 256x128 + attn-proven pipeline protocol --------
#define OBM 256
#define OBN 128
__global__ __launch_bounds__(512, 2) void k_gemm_out(const unsigned short* __restrict__ A,
                                                     const unsigned short* __restrict__ BT,
                                                     float* __restrict__ Cf) {
    __shared__ unsigned short L[2][(OBM + OBN) * 64];   // A rows 0..255, B rows 0..127
    int tid = threadIdx.x;
    int bx = blockIdx.x;
    int swz = (bx & 7) * 32 + (bx >> 3);   // XCD swizzle, bijective (256 = 8*32)
    int rt = swz & 31;                      // 32 row tiles
    int ct = swz >> 5;                      // 8 col tiles
    int r0 = rt * OBM, c0 = ct * OBN;
    int lane = tid & 63, wid = tid >> 6;
    int l15 = lane & 15, grp = lane >> 4;
    int wrow = (wid >> 2) * 128;            // 2 wave-rows
    int wcol = (wid & 3) * 32;              // 4 wave-cols

    f32x4 acc[8][2] = {};

    auto stageA = [&](int bufi, int k0) {
        #pragma unroll
        for (int r = 0; r < 4; ++r) {
            int off = r * 4096 + tid * 8;
            int row = off >> 6;
            int sch = ((off >> 3) & 7) ^ (row & 7);
            gl_lds16(A + (size_t)(r0 + row) * 1024 + k0 + sch * 8, &L[bufi][off]);
        }
    };
    auto stageB = [&](int bufi, int k0) {
        #pragma unroll
        for (int r = 0; r < 2; ++r) {
            int off = r * 4096 + tid * 8;
            int row = off >> 6;
            int sch = ((off >> 3) & 7) ^ (row & 7);
            gl_lds16(BT + (size_t)(c0 + row) * 1024 + k0 + sch * 8, &L[bufi][OBM * 64 + off]);
        }
    };

    // 2-deep prefetch; counted vmcnt (6 gl_lds/wave/tile)
    stageA(0, 0);   stageB(0, 0);
    stageA(1, 64);  stageB(1, 64);

    for (int t = 0; t < 16; ++t) {
        int buf = t & 1;
        if (t < 15) asm volatile("s_waitcnt vmcnt(6)" ::: "memory");
        else        asm volatile("s_waitcnt vmcnt(0)" ::: "memory");
        __builtin_amdgcn_s_barrier();
        __builtin_amdgcn_sched_barrier(0);
        const unsigned short* As = L[buf];
        const unsigned short* Bs = L[buf] + OBM * 64;

        half8 af[8], bf[2];
        #pragma unroll
        for (int i = 0; i < 8; ++i) af[i] = rd_swz(As, wrow + i * 16 + l15, grp * 8);
        #pragma unroll
        for (int j = 0; j < 2; ++j) bf[j] = rd_swz(Bs, wcol + j * 16 + l15, grp * 8);
        __builtin_amdgcn_s_setprio(1);
        #pragma unroll
        for (int i = 0; i < 8; ++i)
            #pragma unroll
            for (int j = 0; j < 2; ++j)
                acc[i][j] = __builtin_amdgcn_mfma_f32_16x16x32_f16(af[i], bf[j], acc[i][j], 0, 0, 0);
        __builtin_amdgcn_s_setprio(0);

        #pragma unroll
        for (int i = 0; i < 8; ++i) af[i] = rd_swz(As, wrow + i * 16 + l15, 32 + grp * 8);
        #pragma unroll
        for (int j = 0; j < 2; ++j) bf[j] = rd_swz(Bs, wcol + j * 16 + l15, 32 + grp * 8);
        __builtin_amdgcn_s_setprio(1);
        #pragma unroll
        for (int i = 0; i < 8; ++i)
            #pragma unroll
            for (int j = 0; j < 2; ++j)
                acc[i][j] = __builtin_amdgcn_mfma_f32_16x16x32_f16(af[i], bf[j], acc[i][j], 0, 0, 0);
        __builtin_amdgcn_s_setprio(0);

        __builtin_amdgcn_sched_barrier(0);
        __builtin_amdgcn_s_barrier();          // all waves done reading buf -> safe to overwrite
        if (t < 14) { stageA(buf, (t + 2) * 64); stageB(buf, (t + 2) * 64); }
    }

    #pragma unroll
    for (int i = 0; i < 8; ++i)
        #pragma unroll
        for (int j = 0; j < 2; ++j)
            #pragma unroll
            for (int reg = 0; reg < 4; ++reg) {
                int r = r0 + wrow + i * 16 + grp * 4 + reg;
                int c = c0 + wcol + j * 16 + l15;
                Cf[(size_t)r * 1024 + c] = acc[i][j][reg];
            }
}

extern "C" void kernel_launch(void* const* d_in, const int* in_sizes, int n_in,
                              void* d_out, int out_size, void* d_ws, size_t ws_size,
                              hipStream_t stream) {
    (void)in_sizes; (void)n_in; (void)out_size; (void)ws_size;
    const float* x  = (const float*)d_in[0];
    const float* Wq = (const float*)d_in[1];
    const float* Wk = (const float*)d_in[2];
    const float* Wv = (const float*)d_in[3];
    const float* Wo = (const float*)d_in[4];

    char* ws = (char*)d_ws;
    unsigned short* Xh   = (unsigned short*)ws;  ws += (size_t)R_TOT * 1024 * 2;
    unsigned short* BTq  = (unsigned short*)ws;  ws += (size_t)N_QKV * 1024 * 2;
    unsigned short* BTo  = (unsigned short*)ws;  ws += (size_t)1024 * 1024 * 2;
    unsigned short* QKV  = (unsigned short*)ws;  ws += (size_t)3 * QKV_ONE * 2;
    unsigned short* Ctx  = (unsigned short*)ws;  ws += (size_t)R_TOT * 1024 * 2;

    k_convert_x<<<dim3(R_TOT * 1024 / 4 / 256), dim3(256), 0, stream>>>(x, Xh);
    k_convert_wqkv<<<dim3(N_QKV * 1024 / 256), dim3(256), 0, stream>>>(Wq, Wk, Wv, BTq);
    k_convert_wo<<<dim3(1024 * 1024 / 256), dim3(256), 0, stream>>>(Wo, BTo);
    k_gemm_qkv<<<dim3(512), dim3(512), 0, stream>>>(Xh, BTq, QKV);
    k_attn<<<dim3(512), dim3(512), 0, stream>>>(QKV, Ctx);
    k_gemm_out<<<dim3(256), dim3(512), 0, stream>>>(Ctx, BTo, (float*)d_out);
}

// Round 17
// 192.375 us; speedup vs baseline: 1.0269x; 1.0269x over previous
//
#include <hip/hip_runtime.h>
#include <hip/hip_bf16.h>

typedef __attribute__((ext_vector_type(8))) short short8;
typedef __attribute__((ext_vector_type(8))) _Float16 half8;
typedef __attribute__((ext_vector_type(4))) float f32x4;
typedef __attribute__((ext_vector_type(16))) float f32x16;
typedef __attribute__((ext_vector_type(4))) unsigned int uint4v;
typedef __attribute__((ext_vector_type(2))) unsigned int uint2v;

#define NB 4
#define NH 16
#define NS 2048
#define ND 1024
#define NM 64
#define R_TOT 8192            // NB*NS
#define N_QKV 3072
#define QKV_ONE 8388608       // NB*NH*NS*NM
#define SCALE_Q 0.18033688011112042f   // (1/8)*log2(e)

static __device__ __forceinline__ unsigned short f2h(float f) {
    _Float16 h = (_Float16)f;   // v_cvt_f16_f32, RNE
    return __builtin_bit_cast(unsigned short, h);
}
static __device__ __forceinline__ unsigned cvtpk_h(float lo, float hiv) {
    unsigned r;   // D.lo = f16(S0), D.hi = f16(S1)
    asm("v_cvt_pkrtz_f16_f32 %0, %1, %2" : "=v"(r) : "v"(lo), "v"(hiv));
    return r;
}
static __device__ __forceinline__ void gl_lds16(const unsigned short* g, unsigned short* l) {
    __builtin_amdgcn_global_load_lds((const __attribute__((address_space(1))) void*)g,
                                     (__attribute__((address_space(3))) void*)l, 16, 0, 0);
}
// swizzled LDS read: tile rows are 64 shorts = 128B = 8 x 16B chunks, XOR chunk with (row&7)
static __device__ __forceinline__ half8 rd_swz(const unsigned short* base, int row, int col) {
    int byte = (row << 7) + (col << 1);
    byte ^= (row & 7) << 4;
    return *(const half8*)((const char*)base + byte);
}

// ---------------- conversions ----------------
__global__ __launch_bounds__(256) void k_convert_x(const float* __restrict__ x,
                                                   unsigned short* __restrict__ xh) {
    int i = blockIdx.x * 256 + threadIdx.x;
    const float4* xp = (const float4*)x;
    float4 v = xp[i];
    ushort4 o;
    o.x = f2h(v.x); o.y = f2h(v.y); o.z = f2h(v.z); o.w = f2h(v.w);
    ((ushort4*)xh)[i] = o;
}

__global__ __launch_bounds__(256) void k_convert_wqkv(const float* __restrict__ Wq,
                                                      const float* __restrict__ Wk,
                                                      const float* __restrict__ Wv,
                                                      unsigned short* __restrict__ BT) {
    int i = blockIdx.x * 256 + threadIdx.x;   // i = n*1024 + d
    int d = i & 1023;
    int n = i >> 10;
    int w = n >> 10;
    int h = (n >> 6) & 15;
    int m = n & 63;
    const float* W = (w == 0) ? Wq : ((w == 1) ? Wk : Wv);
    float v = W[((size_t)h * ND + d) * NM + m];
    if (w == 0) v *= SCALE_Q;
    BT[i] = f2h(v);
}

__global__ __launch_bounds__(256) void k_convert_wo(const float* __restrict__ Wo,
                                                    unsigned short* __restrict__ BTo) {
    int i = blockIdx.x * 256 + threadIdx.x;   // i = d*1024 + n
    int n = i & 1023;
    int d = i >> 10;
    BTo[i] = f2h(Wo[(size_t)n * ND + d]);
}

// ---------------- QKV projection GEMM: 256x192 tile, issue-early staging (R13-proven) ------
#define QBM 256
#define QBN 192
__global__ __launch_bounds__(512, 2) void k_gemm_qkv(const unsigned short* __restrict__ A,
                                                     const unsigned short* __restrict__ BT,
                                                     unsigned short* __restrict__ qkv) {
    __shared__ unsigned short L[2][(QBM + QBN) * 64];   // A rows 0..255, B rows 0..191
    int tid = threadIdx.x;
    int bx = blockIdx.x;
    int swz = (bx & 7) * 64 + (bx >> 3);   // XCD swizzle, bijective (512 = 8*64)
    int rt = swz & 31;                      // 32 row tiles
    int ct = swz >> 5;                      // 16 col tiles
    int r0 = rt * QBM, c0 = ct * QBN;
    int lane = tid & 63, wid = tid >> 6;
    int l15 = lane & 15, grp = lane >> 4;
    int wrow = (wid >> 2) * 128;            // 2 wave-rows
    int wcol = (wid & 3) * 48;              // 4 wave-cols

    f32x4 acc[8][3] = {};

    auto stageA = [&](int bufi, int k0) {
        #pragma unroll
        for (int r = 0; r < 4; ++r) {
            int off = r * 4096 + tid * 8;
            int row = off >> 6;
            int sch = ((off >> 3) & 7) ^ (row & 7);
            gl_lds16(A + (size_t)(r0 + row) * 1024 + k0 + sch * 8, &L[bufi][off]);
        }
    };
    auto stageB = [&](int bufi, int k0) {
        #pragma unroll
        for (int r = 0; r < 3; ++r) {
            int off = r * 4096 + tid * 8;
            int row = off >> 6;
            int sch = ((off >> 3) & 7) ^ (row & 7);
            gl_lds16(BT + (size_t)(c0 + row) * 1024 + k0 + sch * 8, &L[bufi][QBM * 64 + off]);
        }
    };

    stageA(0, 0);
    stageB(0, 0);
    asm volatile("s_waitcnt vmcnt(0)" ::: "memory");
    __builtin_amdgcn_s_barrier();

    for (int t = 0; t < 16; ++t) {
        int buf = t & 1;
        const unsigned short* As = L[buf];
        const unsigned short* Bs = L[buf] + QBM * 64;

        half8 af[8], bf[3];
        // phase 0: kstep 0 reads, then issue ALL next-tile staging (max slack)
        #pragma unroll
        for (int i = 0; i < 8; ++i) af[i] = rd_swz(As, wrow + i * 16 + l15, grp * 8);
        #pragma unroll
        for (int j = 0; j < 3; ++j) bf[j] = rd_swz(Bs, wcol + j * 16 + l15, grp * 8);
        if (t < 15) { stageA(buf ^ 1, (t + 1) * 64); stageB(buf ^ 1, (t + 1) * 64); }
        __builtin_amdgcn_sched_barrier(0);
        __builtin_amdgcn_s_setprio(1);
        #pragma unroll
        for (int i = 0; i < 8; ++i)
            #pragma unroll
            for (int j = 0; j < 3; ++j)
                acc[i][j] = __builtin_amdgcn_mfma_f32_16x16x32_f16(af[i], bf[j], acc[i][j], 0, 0, 0);
        __builtin_amdgcn_s_setprio(0);

        // phase 1: kstep 32
        #pragma unroll
        for (int i = 0; i < 8; ++i) af[i] = rd_swz(As, wrow + i * 16 + l15, 32 + grp * 8);
        #pragma unroll
        for (int j = 0; j < 3; ++j) bf[j] = rd_swz(Bs, wcol + j * 16 + l15, 32 + grp * 8);
        __builtin_amdgcn_s_setprio(1);
        #pragma unroll
        for (int i = 0; i < 8; ++i)
            #pragma unroll
            for (int j = 0; j < 3; ++j)
                acc[i][j] = __builtin_amdgcn_mfma_f32_16x16x32_f16(af[i], bf[j], acc[i][j], 0, 0, 0);
        __builtin_amdgcn_s_setprio(0);

        asm volatile("s_waitcnt vmcnt(0)" ::: "memory");
        __builtin_amdgcn_s_barrier();
    }

    // epilogue: scatter to [w][b,h,s,m] (Q,K) / [b,h,m,s] (V^T)
    #pragma unroll
    for (int j = 0; j < 3; ++j) {
        int n_base = c0 + wcol + j * 16;      // multiple of 16, never straddles 1024
        int w = n_base >> 10;
        int nh = n_base + l15;
        int h = (nh >> 6) & 15;
        int m = nh & 63;
        if (w == 2) {
            unsigned short* outp = qkv + 2 * (size_t)QKV_ONE;
            #pragma unroll
            for (int i = 0; i < 8; ++i) {
                int rb = r0 + wrow + i * 16 + grp * 4;
                int bb = rb >> 11, s = rb & 2047;
                ushort4 pv;
                pv.x = f2h(acc[i][j][0]);
                pv.y = f2h(acc[i][j][1]);
                pv.z = f2h(acc[i][j][2]);
                pv.w = f2h(acc[i][j][3]);
                *(ushort4*)(outp + ((size_t)(bb * NH + h) * NM + m) * NS + s) = pv;
            }
        } else {
            unsigned short* outp = qkv + (size_t)w * QKV_ONE;
            #pragma unroll
            for (int i = 0; i < 8; ++i) {
                int rb = r0 + wrow + i * 16 + grp * 4;
                #pragma unroll
                for (int reg = 0; reg < 4; ++reg) {
                    int r = rb + reg;
                    int bb = r >> 11, s = r & 2047;
                    outp[((size_t)(bb * NH + h) * NS + s) * NM + m] = f2h(acc[i][j][reg]);
                }
            }
        }
    }
}

// ---------------- flash attention: R13-exact (8 waves, proven; issue-bound at ~91%) --------
__global__ __launch_bounds__(512) void k_attn(const unsigned short* __restrict__ qkv,
                                              unsigned short* __restrict__ ctx) {
    __shared__ unsigned short Ks[2][4096];   // [t][m] 64x64, chunk-swizzled
    __shared__ unsigned short Vs[2][4096];   // [m][t] 64x64 (V^T), chunk-swizzled

    int tid = threadIdx.x;
    int lane = tid & 63, wid = tid >> 6;     // 8 waves
    int l31 = lane & 31, hi = lane >> 5;

    int bid = blockIdx.x;                    // 512 blocks
    int xcd = bid & 7;                       // one head-group per XCD for L2 reuse
    int j = bid >> 3;                        // 0..63
    int bh = xcd * 8 + (j >> 3);
    int qb = j & 7;                          // 0..7
    int b = bh >> 4, h = bh & 15;

    size_t hb = (size_t)bh * NS * NM;
    const unsigned short* Qg = qkv + hb;
    const unsigned short* Kg = qkv + QKV_ONE + hb;
    const unsigned short* Vt = qkv + 2 * (size_t)QKV_ONE + hb;

    int q0 = qb * 256 + wid * 32;

    half8 qf[4];
    #pragma unroll
    for (int kk = 0; kk < 4; ++kk)
        qf[kk] = *(const half8*)(Qg + (size_t)(q0 + l31) * NM + kk * 16 + hi * 8);

    half8 ones;
    #pragma unroll
    for (int e = 0; e < 8; ++e) ones[e] = (_Float16)1.0f;

    f32x16 accO0 = {}, accO1 = {}, accS = {};

    // staging: 16 segs of 1KB; wave w owns segs {2w, 2w+1}; segs 0-7 = K, 8-15 = V
    const unsigned short* gsrc0;
    const unsigned short* gsrc1;
    unsigned short* lbase0;
    unsigned short* lbase1;
    int step0, step1;
    {
        int seg = wid * 2;
        int off = (seg & 7) * 512 + lane * 8;
        int row = off >> 6;
        int sch = ((off >> 3) & 7) ^ (row & 7);
        if (seg < 8) { gsrc0 = Kg + row * NM + sch * 8; step0 = NM;  lbase0 = &Ks[0][off]; }
        else         { gsrc0 = Vt + (size_t)row * NS + sch * 8; step0 = 1; lbase0 = &Vs[0][off]; }
        seg = wid * 2 + 1;
        off = (seg & 7) * 512 + lane * 8;
        row = off >> 6;
        sch = ((off >> 3) & 7) ^ (row & 7);
        if (seg < 8) { gsrc1 = Kg + row * NM + sch * 8; step1 = NM;  lbase1 = &Ks[0][off]; }
        else         { gsrc1 = Vt + (size_t)row * NS + sch * 8; step1 = 1; lbase1 = &Vs[0][off]; }
    }
    auto stage = [&](int bufi, int t0) {
        gl_lds16(gsrc0 + (size_t)t0 * step0, lbase0 + bufi * 4096);
        gl_lds16(gsrc1 + (size_t)t0 * step1, lbase1 + bufi * 4096);
    };

    // 2-deep prefetch; counted vmcnt (2 loads/wave/tile)
    stage(0, 0);
    stage(1, 64);

    for (int t = 0; t < 32; ++t) {
        int buf = t & 1;
        if (t < 31) asm volatile("s_waitcnt vmcnt(2)" ::: "memory");
        else        asm volatile("s_waitcnt vmcnt(0)" ::: "memory");
        __builtin_amdgcn_s_barrier();          // all 16 segs of tile t in LDS
        __builtin_amdgcn_sched_barrier(0);
        const unsigned short* Kb = Ks[buf];
        const unsigned short* Vb = Vs[buf];

        // S^T[t][q] = mfma(K, Q): col = q = l31, row t' = (reg&3)+8*(reg>>2)+4*hi
        f32x16 s0v = {}, s1v = {};
        __builtin_amdgcn_s_setprio(1);
        #pragma unroll
        for (int kk = 0; kk < 4; ++kk) {
            int col = kk * 16 + hi * 8;
            s0v = __builtin_amdgcn_mfma_f32_32x32x16_f16(rd_swz(Kb, l31, col), qf[kk], s0v, 0, 0, 0);
            s1v = __builtin_amdgcn_mfma_f32_32x32x16_f16(rd_swz(Kb, 32 + l31, col), qf[kk], s1v, 0, 0, 0);
        }
        __builtin_amdgcn_s_setprio(0);

        // exp2 (Q pre-scaled by log2e/8), pack to fp16 pairs (denominator via ones-MFMA)
        unsigned pk0[8], pk1[8];
        #pragma unroll
        for (int jj = 0; jj < 8; ++jj) {
            float a0 = __builtin_amdgcn_exp2f(s0v[2 * jj]);
            float b0 = __builtin_amdgcn_exp2f(s0v[2 * jj + 1]);
            float a1 = __builtin_amdgcn_exp2f(s1v[2 * jj]);
            float b1 = __builtin_amdgcn_exp2f(s1v[2 * jj + 1]);
            pk0[jj] = cvtpk_h(a0, b0);
            pk1[jj] = cvtpk_h(a1, b1);
        }

        // PV A-fragment via hazard-modeled builtin permlane32_swap (vdst.hi <-> vsrc.lo)
        __builtin_amdgcn_s_setprio(1);
        #pragma unroll
        for (int kt = 0; kt < 4; ++kt) {
            unsigned w0, w1, w2, w3;
            if (kt < 2) {
                int base = (kt & 1) * 4;
                w0 = pk0[base + 0]; w1 = pk0[base + 1];
                w2 = pk0[base + 2]; w3 = pk0[base + 3];
            } else {
                int base = (kt & 1) * 4;
                w0 = pk1[base + 0]; w1 = pk1[base + 1];
                w2 = pk1[base + 2]; w3 = pk1[base + 3];
            }
            uint2v r02 = __builtin_amdgcn_permlane32_swap(w0, w2, false, false);
            uint2v r13 = __builtin_amdgcn_permlane32_swap(w1, w3, false, false);
            uint4v av;
            av[0] = r02[0]; av[1] = r13[0]; av[2] = r02[1]; av[3] = r13[1];
            half8 af = __builtin_bit_cast(half8, av);
            int col = kt * 16 + hi * 8;
            accO0 = __builtin_amdgcn_mfma_f32_32x32x16_f16(af, rd_swz(Vb, l31, col), accO0, 0, 0, 0);
            accO1 = __builtin_amdgcn_mfma_f32_32x32x16_f16(af, rd_swz(Vb, 32 + l31, col), accO1, 0, 0, 0);
            accS  = __builtin_amdgcn_mfma_f32_32x32x16_f16(af, ones, accS, 0, 0, 0);
        }
        __builtin_amdgcn_s_setprio(0);

        __builtin_amdgcn_sched_barrier(0);
        __builtin_amdgcn_s_barrier();          // all waves done READING buf -> safe to overwrite
        if (t < 30) stage(buf, (t + 2) * 64);
    }

    // denominators in accS (same (reg,hi)->q map as accO) -- fully in-register
    #pragma unroll
    for (int reg = 0; reg < 16; ++reg) {
        int q = (reg & 3) + 8 * (reg >> 2) + 4 * hi;
        float linv = 1.0f / accS[reg];
        size_t ob = ((size_t)b * NS + (q0 + q)) * ND + h * 64 + l31;
        ctx[ob] = f2h(accO0[reg] * linv);
        ctx[ob + 32] = f2h(accO1[reg] * linv);
    }
}

// ---------------- output projection GEMM (gl_lds BK=64 template, R13-exact) ----------------
__global__ __launch_bounds__(256) void k_gemm_out(const unsigned short* __restrict__ A,
                                                  const unsigned short* __restrict__ BT,
                                                  float* __restrict__ Cf) {
    __shared__ unsigned short As[128 * 64];
    __shared__ unsigned short Bs[128 * 64];
    int tid = threadIdx.x;
    int bx = blockIdx.x;
    int rt = bx & 63, ct = bx >> 6;
    int r0 = rt * 128, c0 = ct * 128;
    int lane = tid & 63, wid = tid >> 6;
    int l15 = lane & 15, grp = lane >> 4;
    int wr = (wid >> 1) * 64, wc = (wid & 1) * 64;
    f32x4 acc[4][4] = {};

    for (int k0 = 0; k0 < 1024; k0 += 64) {
        #pragma unroll
        for (int i = 0; i < 4; ++i) {
            int seg = wid * 4 + i;
            int row = seg * 8 + (lane >> 3);
            int sch = (lane & 7) ^ (row & 7);
            gl_lds16(A + (size_t)(r0 + row) * 1024 + k0 + sch * 8, As + seg * 512 + lane * 8);
            gl_lds16(BT + (size_t)(c0 + row) * 1024 + k0 + sch * 8, Bs + seg * 512 + lane * 8);
        }
        __syncthreads();
        #pragma unroll
        for (int ks = 0; ks < 64; ks += 32) {
            half8 af[4], bf[4];
            #pragma unroll
            for (int i = 0; i < 4; ++i)
                af[i] = rd_swz(As, wr + i * 16 + l15, ks + grp * 8);
            #pragma unroll
            for (int j = 0; j < 4; ++j)
                bf[j] = rd_swz(Bs, wc + j * 16 + l15, ks + grp * 8);
            #pragma unroll
            for (int i = 0; i < 4; ++i)
                #pragma unroll
                for (int j = 0; j < 4; ++j)
                    acc[i][j] = __builtin_amdgcn_mfma_f32_16x16x32_f16(af[i], bf[j], acc[i][j], 0, 0, 0);
        }
        __syncthreads();
    }
    #pragma unroll
    for (int i = 0; i < 4; ++i)
        #pragma unroll
        for (int j = 0; j < 4; ++j)
            #pragma unroll
            for (int reg = 0; reg < 4; ++reg) {
                int r = r0 + wr + i * 16 + grp * 4 + reg;
                int c = c0 + wc + j * 16 + l15;
                Cf[(size_t)r * 1024 + c] = acc[i][j][reg];
            }
}

extern "C" void kernel_launch(void* const* d_in, const int* in_sizes, int n_in,
                              void* d_out, int out_size, void* d_ws, size_t ws_size,
                              hipStream_t stream) {
    (void)in_sizes; (void)n_in; (void)out_size; (void)ws_size;
    const float* x  = (const float*)d_in[0];
    const float* Wq = (const float*)d_in[1];
    const float* Wk = (const float*)d_in[2];
    const float* Wv = (const float*)d_in[3];
    const float* Wo = (const float*)d_in[4];

    char* ws = (char*)d_ws;
    unsigned short* Xh   = (unsigned short*)ws;  ws += (size_t)R_TOT * 1024 * 2;
    unsigned short* BTq  = (unsigned short*)ws;  ws += (size_t)N_QKV * 1024 * 2;
    unsigned short* BTo  = (unsigned short*)ws;  ws += (size_t)1024 * 1024 * 2;
    unsigned short* QKV  = (unsigned short*)ws;  ws += (size_t)3 * QKV_ONE * 2;
    unsigned short* Ctx  = (unsigned short*)ws;  ws += (size_t)R_TOT * 1024 * 2;

    k_convert_x<<<dim3(R_TOT * 1024 / 4 / 256), dim3(256), 0, stream>>>(x, Xh);
    k_convert_wqkv<<<dim3(N_QKV * 1024 / 256), dim3(256), 0, stream>>>(Wq, Wk, Wv, BTq);
    k_convert_wo<<<dim3(1024 * 1024 / 256), dim3(256), 0, stream>>>(Wo, BTo);
    k_gemm_qkv<<<dim3(512), dim3(512), 0, stream>>>(Xh, BTq, QKV);
    k_attn<<<dim3(512), dim3(512), 0, stream>>>(QKV, Ctx);
    k_gemm_out<<<dim3(64 * 8), dim3(256), 0, stream>>>(Ctx, BTo, (float*)d_out);
}